// Round 13
// baseline (115.358 us; speedup 1.0000x reference)
//
#include <hip/hip_runtime.h>
#include <hip/hip_bf16.h>

// ROUND 13: A/B + visibility. gemms reverted to round-10 config (best known);
// eager attn kept; attn grid x4 (ignored blockIdx.y, idempotent) to surface counters.

typedef __bf16 bfv8 __attribute__((ext_vector_type(8)));
typedef float f32x4 __attribute__((ext_vector_type(4)));
typedef unsigned short u16;
typedef unsigned int u32;
typedef u16 u16x8 __attribute__((ext_vector_type(8)));

__device__ __forceinline__ float bf2f(u16 u){ union{u32 i; float f;} x; x.i=(u32)u<<16; return x.f; }
__device__ __forceinline__ u16 f2bf(float f){ union{float f; u32 i;} x; x.f=f; u32 i=x.i; return (u16)((i + 0x7FFFu + ((i>>16)&1u))>>16); }

// async global->LDS, 16B per lane: LDS dest = wave-uniform base + lane*16, global src per-lane
__device__ __forceinline__ void gl16(const void* g, void* l){
  __builtin_amdgcn_global_load_lds((const __attribute__((address_space(1))) unsigned int*)g,
                                   (__attribute__((address_space(3))) unsigned int*)l, 16, 0, 0);
}

// ---------- fused prep: cvt x->bf16 | transpose w_qkv | transpose w_out | bias gather ----------
__global__ __launch_bounds__(256) void prep_k(const float* __restrict__ x, u16* __restrict__ xb,
                                              const float* __restrict__ w_qkv, u16* __restrict__ wT,
                                              const float* __restrict__ w_out, u16* __restrict__ woT,
                                              const float* __restrict__ bt, const int* __restrict__ ridx,
                                              u16* __restrict__ biasp2){
  __shared__ u16 tile[32][34];
  const int bid = blockIdx.x, tid = threadIdx.x;
  if (bid < 2048){                       // cvt: 2048*256*8 = 4.19M elems
    int i = (bid*256 + tid)*8;
    float4 a = *(const float4*)&x[i];
    float4 b = *(const float4*)&x[i+4];
    u16 r[8] = { f2bf(a.x),f2bf(a.y),f2bf(a.z),f2bf(a.w), f2bf(b.x),f2bf(b.y),f2bf(b.z),f2bf(b.w) };
    *(int4*)&xb[i] = *(int4*)r;
  } else if (bid < 2048+192){            // transpose w_qkv [256][768] -> wT [768][256]
    int b2 = bid - 2048;
    int c0 = (b2 % 24)*32, r0 = (b2/24)*32;
    int tx = tid & 31, ty = tid >> 5;
    #pragma unroll
    for(int dy=0; dy<32; dy+=8) tile[ty+dy][tx] = f2bf(w_qkv[(size_t)(r0+ty+dy)*768 + (c0+tx)]);
    __syncthreads();
    #pragma unroll
    for(int dy=0; dy<32; dy+=8) wT[(size_t)(c0+ty+dy)*256 + (r0+tx)] = tile[tx][ty+dy];
  } else if (bid < 2048+192+64){         // transpose w_out [256][256] -> woT [256][256]
    int b3 = bid - (2048+192);
    int c0 = (b3 & 7)*32, r0 = (b3 >> 3)*32;
    int tx = tid & 31, ty = tid >> 5;
    #pragma unroll
    for(int dy=0; dy<32; dy+=8) tile[ty+dy][tx] = f2bf(w_out[(size_t)(r0+ty+dy)*256 + (c0+tx)]);
    __syncthreads();
    #pragma unroll
    for(int dy=0; dy<32; dy+=8) woT[(size_t)(c0+ty+dy)*256 + (r0+tx)] = tile[tx][ty+dy];
  } else {                               // bias gather: 524288 bf16, layout [h][rb][lane][ch][e]
    const float L2E = 1.4426950408889634f;
    int idx = (bid - (2048+192+64))*256 + tid;
    int e = idx & 7, ch = (idx>>3)&7, lane = (idx>>6)&63, rb = (idx>>12)&15, h = (idx>>16)&7;
    int ll = lane & 15, lg = lane >> 4;
    int tj = ch*2 + (e>>2), r = e & 3;
    int q = rb*16 + ll, k = 16*tj + 4*lg + r;
    biasp2[idx] = f2bf(bt[ridx[q*256 + k]*8 + h] * L2E);
  }
}

// ---------- m97-style GEMM: C[M][N] = A[M][K]*Bt[N][K]^T (+bias), BK=64, global_load_lds ----------
template<bool BIAS, typename OUT, int TM>
__global__ __launch_bounds__(256) void gemm_k(const u16* __restrict__ A, const u16* __restrict__ Bt,
                         const float* __restrict__ bias, OUT* __restrict__ C, int M, int N, int K){
  constexpr int MI = TM/32;              // M-frags per wave
  __shared__ u16 As[TM*64];              // linear, no padding (global_load_lds requirement)
  __shared__ u16 Bs[128*64];
  const int tid = threadIdx.x, lane = tid & 63, wv = tid >> 6;
  const int lg = lane >> 4, ll = lane & 15;
  const int wr = (wv >> 1)*(TM/2), wc = (wv & 1)*64;
  const size_t m0 = (size_t)blockIdx.x*TM;
  const int n0 = blockIdx.y*128;
  const int lrow = lane >> 3, lcol = (lane & 7)*8;   // 16B/lane: 8 rows x 64 cols per 1KB chunk
  f32x4 acc[MI][4] = {};
  for(int k0=0; k0<K; k0+=64){
    #pragma unroll
    for(int c=0;c<MI;++c){               // A: TM/8 chunks total, MI per wave
      int rowbase = (wv*MI + c)*8;
      gl16(&A[(m0 + rowbase + lrow)*(size_t)K + k0 + lcol], &As[rowbase*64]);
    }
    #pragma unroll
    for(int c=0;c<4;++c){                // B: 16 chunks, 4 per wave
      int rowbase = (wv*4 + c)*8;
      gl16(&Bt[(size_t)(n0 + rowbase + lrow)*K + k0 + lcol], &Bs[rowbase*64]);
    }
    __syncthreads();                     // drains vmcnt(0): staged data visible
    bfv8 af[MI][2], bf[4][2];
    #pragma unroll
    for(int i=0;i<MI;++i)
      #pragma unroll
      for(int kh=0;kh<2;++kh) af[i][kh] = *(const bfv8*)&As[(wr+16*i+ll)*64 + kh*32 + lg*8];
    #pragma unroll
    for(int j=0;j<4;++j)
      #pragma unroll
      for(int kh=0;kh<2;++kh) bf[j][kh] = *(const bfv8*)&Bs[(wc+16*j+ll)*64 + kh*32 + lg*8];
    #pragma unroll
    for(int kh=0;kh<2;++kh)
      #pragma unroll
      for(int i=0;i<MI;++i)
        #pragma unroll
        for(int j=0;j<4;++j)
          acc[i][j] = __builtin_amdgcn_mfma_f32_16x16x32_bf16(af[i][kh], bf[j][kh], acc[i][j], 0,0,0);
    __syncthreads();
  }
  #pragma unroll
  for(int i=0;i<MI;++i)
    #pragma unroll
    for(int j=0;j<4;++j){
      int col = n0 + wc + 16*j + ll;
      float bv = 0.f;
      if (BIAS) bv = bias[col];
      #pragma unroll
      for(int r=0;r<4;++r){
        size_t row = m0 + wr + 16*i + lg*4 + r;
        float v = acc[i][j][r] + bv;
        if constexpr (sizeof(OUT) == 2) C[row*(size_t)N + col] = f2bf(v);
        else                            C[row*(size_t)N + col] = v;
      }
    }
}

// ---------- fused attention per (b,h): 8 waves, eager per-c softmax pipeline ----------
// VGPR target <= 64 (launch_bounds(512,8)). blockIdx.y IGNORED (x4 diagnostic duplication).
__global__ __launch_bounds__(512,8) void attn_k(const u16* __restrict__ qkv, const u16* __restrict__ biasp2, u16* __restrict__ attnb){
  __shared__ u16 Ks[256*40];
  __shared__ u16 Vt[32*264];
  const int i = blockIdx.x;
  const int b = i & 63, h = i >> 6;
  const int tid = threadIdx.x, lane = tid & 63, wv = tid >> 6;   // wv in [0,8)
  const int lg = lane >> 4, ll = lane & 15;
  const u16* qb = qkv + (size_t)b*256*768;
  // stage K [256][32] pitch 40 (1024 8-elem chunks, 512 threads x 2)
  #pragma unroll
  for(int p=0;p<2;++p){
    int ch = tid + p*512;
    int j = ch >> 2, d8 = (ch & 3)*8;
    *(int4*)&Ks[j*40 + d8] = *(const int4*)&qb[(size_t)j*768 + 256 + h*32 + d8];
  }
  // stage V^T [32][264] at permuted col jp(k) = 32*(k>>5) + 8*((k>>2)&3) + 4*((k>>4)&1) + (k&3)
  #pragma unroll
  for(int it=0; it<8; ++it){
    int e = tid + it*512;
    int j = e >> 4, dp = (e & 15)*2;
    int jp = ((j>>5)<<5) + 8*((j>>2)&3) + 4*((j>>4)&1) + (j&3);
    u32 v = *(const u32*)&qb[(size_t)j*768 + 512 + h*32 + dp];
    Vt[dp*264 + jp]     = (u16)(v & 0xffffu);
    Vt[(dp+1)*264 + jp] = (u16)(v >> 16);
  }
  __syncthreads();
  const float SCALE2 = 0.17677669529663687f * 1.4426950408889634f;
  const f32x4 zero = {0.f,0.f,0.f,0.f};
  #pragma unroll 1
  for(int iter=0; iter<2; ++iter){
    const int q0 = iter*128 + wv*16;
    const u16* bp = biasp2 + ((((size_t)h*16 + (q0>>4))*64 + lane) << 6);
    bfv8 qf = *(const bfv8*)&qb[(size_t)(q0+ll)*768 + h*32 + lg*8];
    float sum = 0.f;
    f32x4 o0 = zero, o1 = zero;
    #pragma unroll
    for(int c=0;c<8;++c){
      u16x8 bc = *(const u16x8*)&bp[c*8];
      bfv8 kf0 = *(const bfv8*)&Ks[(16*(2*c)+ll)*40 + lg*8];
      bfv8 kf1 = *(const bfv8*)&Ks[(16*(2*c+1)+ll)*40 + lg*8];
      f32x4 s0 = __builtin_amdgcn_mfma_f32_16x16x32_bf16(kf0, qf, zero, 0,0,0);
      f32x4 s1 = __builtin_amdgcn_mfma_f32_16x16x32_bf16(kf1, qf, zero, 0,0,0);
      f32x4 p0, p1;
      #pragma unroll
      for(int r=0;r<4;++r){
        p0[r] = exp2f(fmaf(s0[r], SCALE2, bf2f(bc[r])));
        p1[r] = exp2f(fmaf(s1[r], SCALE2, bf2f(bc[4+r])));
      }
      sum += (p0[0]+p0[1]+p0[2]+p0[3]) + (p1[0]+p1[1]+p1[2]+p1[3]);
      union { u32 u[4]; bfv8 v; } pu;
      asm("v_cvt_pk_bf16_f32 %0, %1, %2" : "=v"(pu.u[0]) : "v"(p0[0]), "v"(p0[1]));
      asm("v_cvt_pk_bf16_f32 %0, %1, %2" : "=v"(pu.u[1]) : "v"(p0[2]), "v"(p0[3]));
      asm("v_cvt_pk_bf16_f32 %0, %1, %2" : "=v"(pu.u[2]) : "v"(p1[0]), "v"(p1[1]));
      asm("v_cvt_pk_bf16_f32 %0, %1, %2" : "=v"(pu.u[3]) : "v"(p1[2]), "v"(p1[3]));
      bfv8 vf0 = *(const bfv8*)&Vt[(ll)*264      + 32*c + lg*8];
      bfv8 vf1 = *(const bfv8*)&Vt[(16+ll)*264   + 32*c + lg*8];
      o0 = __builtin_amdgcn_mfma_f32_16x16x32_bf16(pu.v, vf0, o0, 0,0,0);
      o1 = __builtin_amdgcn_mfma_f32_16x16x32_bf16(pu.v, vf1, o1, 0,0,0);
    }
    sum += __shfl_xor(sum,16);
    sum += __shfl_xor(sum,32);
    float rinv = 1.0f/sum;
    #pragma unroll
    for(int r=0;r<4;++r){
      float rl = __shfl(rinv, 4*lg + r);
      int row = q0 + 4*lg + r;
      attnb[((size_t)b*256 + row)*256 + h*32 + ll]      = f2bf(o0[r]*rl);
      attnb[((size_t)b*256 + row)*256 + h*32 + 16 + ll] = f2bf(o1[r]*rl);
    }
  }
}

extern "C" void kernel_launch(void* const* d_in, const int* in_sizes, int n_in,
                              void* d_out, int out_size, void* d_ws, size_t ws_size,
                              hipStream_t stream) {
  const float* x     = (const float*)d_in[0];   // [64][256][256] f32
  const float* w_qkv = (const float*)d_in[1];   // [256][768] f32
  const float* btab  = (const float*)d_in[2];   // [961][8] f32
  const float* w_out = (const float*)d_in[3];   // [256][256] f32
  const float* b_out = (const float*)d_in[4];   // [256] f32
  const int*   ridx  = (const int*)d_in[5];     // [65536] int32
  float* out = (float*)d_out;                   // [64][256][256] f32

  char* ws = (char*)d_ws;
  size_t off = 0;
  u16*   xb     = (u16*)(ws + off); off += (size_t)64*256*256*2;   // 8.39 MB
  u16*   wT     = (u16*)(ws + off); off += (size_t)768*256*2;      // 0.39 MB
  u16*   woT    = (u16*)(ws + off); off += (size_t)256*256*2;      // 0.13 MB
  u16*   biasp2 = (u16*)(ws + off); off += (size_t)524288*2;       // 1.05 MB
  u16*   qkvb   = (u16*)(ws + off); off += (size_t)64*256*768*2;   // 25.17 MB
  u16*   attnb  = (u16*)(ws + off); off += (size_t)64*256*256*2;   // 8.39 MB

  prep_k<<<2048+192+64+2048,256,0,stream>>>(x, xb, w_qkv, wT, w_out, woT, btab, ridx, biasp2);
  gemm_k<false,u16,128><<<dim3(128,6),256,0,stream>>>(xb, wT, nullptr, qkvb, 16384, 768, 256);
  attn_k<<<dim3(512,4),512,0,stream>>>(qkvb, biasp2, attnb);   // x4 DIAGNOSTIC amplification
  gemm_k<true,float,64><<<dim3(256,2),256,0,stream>>>(attnb, woT, b_out, out, 16384, 256, 256);
}

// Round 15
// 61.853 us; speedup vs baseline: 1.8650x; 1.8650x over previous
//
#include <hip/hip_runtime.h>
#include <hip/hip_bf16.h>

typedef __bf16 bfv8 __attribute__((ext_vector_type(8)));
typedef float f32x4 __attribute__((ext_vector_type(4)));
typedef unsigned short u16;
typedef unsigned int u32;
typedef u16 u16x8 __attribute__((ext_vector_type(8)));

__device__ __forceinline__ float bf2f(u16 u){ union{u32 i; float f;} x; x.i=(u32)u<<16; return x.f; }
__device__ __forceinline__ u16 f2bf(float f){ union{float f; u32 i;} x; x.f=f; u32 i=x.i; return (u16)((i + 0x7FFFu + ((i>>16)&1u))>>16); }

// async global->LDS, 16B per lane: LDS dest = wave-uniform base + lane*16, global src per-lane
__device__ __forceinline__ void gl16(const void* g, void* l){
  __builtin_amdgcn_global_load_lds((const __attribute__((address_space(1))) unsigned int*)g,
                                   (__attribute__((address_space(3))) unsigned int*)l, 16, 0, 0);
}

// ---------- fused prep: cvt x->bf16 | transpose w_qkv | transpose w_out | bias gather ----------
__global__ __launch_bounds__(256) void prep_k(const float* __restrict__ x, u16* __restrict__ xb,
                                              const float* __restrict__ w_qkv, u16* __restrict__ wT,
                                              const float* __restrict__ w_out, u16* __restrict__ woT,
                                              const float* __restrict__ bt, const int* __restrict__ ridx,
                                              u16* __restrict__ biasp2){
  __shared__ u16 tile[32][34];
  const int bid = blockIdx.x, tid = threadIdx.x;
  if (bid < 2048){                       // cvt: 2048*256*8 = 4.19M elems
    int i = (bid*256 + tid)*8;
    float4 a = *(const float4*)&x[i];
    float4 b = *(const float4*)&x[i+4];
    u16 r[8] = { f2bf(a.x),f2bf(a.y),f2bf(a.z),f2bf(a.w), f2bf(b.x),f2bf(b.y),f2bf(b.z),f2bf(b.w) };
    *(int4*)&xb[i] = *(int4*)r;
  } else if (bid < 2048+192){            // transpose w_qkv [256][768] -> wT [768][256]
    int b2 = bid - 2048;
    int c0 = (b2 % 24)*32, r0 = (b2/24)*32;
    int tx = tid & 31, ty = tid >> 5;
    #pragma unroll
    for(int dy=0; dy<32; dy+=8) tile[ty+dy][tx] = f2bf(w_qkv[(size_t)(r0+ty+dy)*768 + (c0+tx)]);
    __syncthreads();
    #pragma unroll
    for(int dy=0; dy<32; dy+=8) wT[(size_t)(c0+ty+dy)*256 + (r0+tx)] = tile[tx][ty+dy];
  } else if (bid < 2048+192+64){         // transpose w_out [256][256] -> woT [256][256]
    int b3 = bid - (2048+192);
    int c0 = (b3 & 7)*32, r0 = (b3 >> 3)*32;
    int tx = tid & 31, ty = tid >> 5;
    #pragma unroll
    for(int dy=0; dy<32; dy+=8) tile[ty+dy][tx] = f2bf(w_out[(size_t)(r0+ty+dy)*256 + (c0+tx)]);
    __syncthreads();
    #pragma unroll
    for(int dy=0; dy<32; dy+=8) woT[(size_t)(c0+ty+dy)*256 + (r0+tx)] = tile[tx][ty+dy];
  } else {                               // bias gather: 524288 bf16, layout [h][rb][lane][ch][e]
    const float L2E = 1.4426950408889634f;
    int idx = (bid - (2048+192+64))*256 + tid;
    int e = idx & 7, ch = (idx>>3)&7, lane = (idx>>6)&63, rb = (idx>>12)&15, h = (idx>>16)&7;
    int ll = lane & 15, lg = lane >> 4;
    int tj = ch*2 + (e>>2), r = e & 3;
    int q = rb*16 + ll, k = 16*tj + 4*lg + r;
    biasp2[idx] = f2bf(bt[ridx[q*256 + k]*8 + h] * L2E);
  }
}

// ---------- m97-style GEMM: C[M][N] = A[M][K]*Bt[N][K]^T (+bias), BK=64, global_load_lds ----------
template<bool BIAS, typename OUT, int TM>
__global__ __launch_bounds__(256) void gemm_k(const u16* __restrict__ A, const u16* __restrict__ Bt,
                         const float* __restrict__ bias, OUT* __restrict__ C, int M, int N, int K){
  constexpr int MI = TM/32;              // M-frags per wave
  __shared__ u16 As[TM*64];              // linear, no padding (global_load_lds requirement)
  __shared__ u16 Bs[128*64];
  const int tid = threadIdx.x, lane = tid & 63, wv = tid >> 6;
  const int lg = lane >> 4, ll = lane & 15;
  const int wr = (wv >> 1)*(TM/2), wc = (wv & 1)*64;
  const size_t m0 = (size_t)blockIdx.x*TM;
  const int n0 = blockIdx.y*128;
  const int lrow = lane >> 3, lcol = (lane & 7)*8;   // 16B/lane: 8 rows x 64 cols per 1KB chunk
  f32x4 acc[MI][4] = {};
  for(int k0=0; k0<K; k0+=64){
    #pragma unroll
    for(int c=0;c<MI;++c){               // A: TM/8 chunks total, MI per wave
      int rowbase = (wv*MI + c)*8;
      gl16(&A[(m0 + rowbase + lrow)*(size_t)K + k0 + lcol], &As[rowbase*64]);
    }
    #pragma unroll
    for(int c=0;c<4;++c){                // B: 16 chunks, 4 per wave
      int rowbase = (wv*4 + c)*8;
      gl16(&Bt[(size_t)(n0 + rowbase + lrow)*K + k0 + lcol], &Bs[rowbase*64]);
    }
    __syncthreads();                     // drains vmcnt(0): staged data visible
    bfv8 af[MI][2], bf[4][2];
    #pragma unroll
    for(int i=0;i<MI;++i)
      #pragma unroll
      for(int kh=0;kh<2;++kh) af[i][kh] = *(const bfv8*)&As[(wr+16*i+ll)*64 + kh*32 + lg*8];
    #pragma unroll
    for(int j=0;j<4;++j)
      #pragma unroll
      for(int kh=0;kh<2;++kh) bf[j][kh] = *(const bfv8*)&Bs[(wc+16*j+ll)*64 + kh*32 + lg*8];
    #pragma unroll
    for(int kh=0;kh<2;++kh)
      #pragma unroll
      for(int i=0;i<MI;++i)
        #pragma unroll
        for(int j=0;j<4;++j)
          acc[i][j] = __builtin_amdgcn_mfma_f32_16x16x32_bf16(af[i][kh], bf[j][kh], acc[i][j], 0,0,0);
    __syncthreads();
  }
  #pragma unroll
  for(int i=0;i<MI;++i)
    #pragma unroll
    for(int j=0;j<4;++j){
      int col = n0 + wc + 16*j + ll;
      float bv = 0.f;
      if (BIAS) bv = bias[col];
      #pragma unroll
      for(int r=0;r<4;++r){
        size_t row = m0 + wr + 16*i + lg*4 + r;
        float v = acc[i][j][r] + bv;
        if constexpr (sizeof(OUT) == 2) C[row*(size_t)N + col] = f2bf(v);
        else                            C[row*(size_t)N + col] = v;
      }
    }
}

// ---------- fused attention: 1024 blocks = (b,h) x half; 8 waves x 16 q-rows, NO iter loop ----------
// r12-validated body verbatim; only q0 = half*128 + wv*16 and grid doubled.
// Occupancy: 4 blocks/CU requested (LDS 37.4KB -> 3-4 granted) x 8 waves = 24-32 waves/CU,
// vs r12's grid-capped 2 blocks/CU = 16. Blocks u and u+512 share (b,h) -> same XCD L2.
__global__ __launch_bounds__(512,8) void attn_k(const u16* __restrict__ qkv, const u16* __restrict__ biasp2, u16* __restrict__ attnb){
  __shared__ u16 Ks[256*40];
  __shared__ u16 Vt[32*264];
  const int u = blockIdx.x & 511, half = blockIdx.x >> 9;
  const int b = u & 63, h = u >> 6;
  const int tid = threadIdx.x, lane = tid & 63, wv = tid >> 6;   // wv in [0,8)
  const int lg = lane >> 4, ll = lane & 15;
  const u16* qb = qkv + (size_t)b*256*768;
  // stage K [256][32] pitch 40 (1024 16B chunks, 512 threads x 2)
  #pragma unroll
  for(int p=0;p<2;++p){
    int ch = tid + p*512;
    int j = ch >> 2, d8 = (ch & 3)*8;
    *(int4*)&Ks[j*40 + d8] = *(const int4*)&qb[(size_t)j*768 + 256 + h*32 + d8];
  }
  // stage V^T [32][264] at permuted col jp(k) = 32*(k>>5) + 8*((k>>2)&3) + 4*((k>>4)&1) + (k&3)
  #pragma unroll
  for(int it=0; it<8; ++it){
    int e = tid + it*512;
    int j = e >> 4, dp = (e & 15)*2;
    int jp = ((j>>5)<<5) + 8*((j>>2)&3) + 4*((j>>4)&1) + (j&3);
    u32 v = *(const u32*)&qb[(size_t)j*768 + 512 + h*32 + dp];
    Vt[dp*264 + jp]     = (u16)(v & 0xffffu);
    Vt[(dp+1)*264 + jp] = (u16)(v >> 16);
  }
  __syncthreads();
  const float SCALE2 = 0.17677669529663687f * 1.4426950408889634f;
  const f32x4 zero = {0.f,0.f,0.f,0.f};
  const int q0 = half*128 + wv*16;
  const u16* bp = biasp2 + ((((size_t)h*16 + (q0>>4))*64 + lane) << 6);
  bfv8 qf = *(const bfv8*)&qb[(size_t)(q0+ll)*768 + h*32 + lg*8];
  float sum = 0.f;
  f32x4 o0 = zero, o1 = zero;
  #pragma unroll
  for(int c=0;c<8;++c){
    // bias chunk c: tj=2c (elems 0-3), tj=2c+1 (elems 4-7)
    u16x8 bc = *(const u16x8*)&bp[c*8];
    bfv8 kf0 = *(const bfv8*)&Ks[(16*(2*c)+ll)*40 + lg*8];
    bfv8 kf1 = *(const bfv8*)&Ks[(16*(2*c+1)+ll)*40 + lg*8];
    f32x4 s0 = __builtin_amdgcn_mfma_f32_16x16x32_bf16(kf0, qf, zero, 0,0,0);
    f32x4 s1 = __builtin_amdgcn_mfma_f32_16x16x32_bf16(kf1, qf, zero, 0,0,0);
    f32x4 p0, p1;
    #pragma unroll
    for(int r=0;r<4;++r){
      p0[r] = exp2f(fmaf(s0[r], SCALE2, bf2f(bc[r])));
      p1[r] = exp2f(fmaf(s1[r], SCALE2, bf2f(bc[4+r])));
    }
    sum += (p0[0]+p0[1]+p0[2]+p0[3]) + (p1[0]+p1[1]+p1[2]+p1[3]);
    union { u32 u[4]; bfv8 v; } pu;
    asm("v_cvt_pk_bf16_f32 %0, %1, %2" : "=v"(pu.u[0]) : "v"(p0[0]), "v"(p0[1]));
    asm("v_cvt_pk_bf16_f32 %0, %1, %2" : "=v"(pu.u[1]) : "v"(p0[2]), "v"(p0[3]));
    asm("v_cvt_pk_bf16_f32 %0, %1, %2" : "=v"(pu.u[2]) : "v"(p1[0]), "v"(p1[1]));
    asm("v_cvt_pk_bf16_f32 %0, %1, %2" : "=v"(pu.u[3]) : "v"(p1[2]), "v"(p1[3]));
    bfv8 vf0 = *(const bfv8*)&Vt[(ll)*264      + 32*c + lg*8];
    bfv8 vf1 = *(const bfv8*)&Vt[(16+ll)*264   + 32*c + lg*8];
    o0 = __builtin_amdgcn_mfma_f32_16x16x32_bf16(pu.v, vf0, o0, 0,0,0);
    o1 = __builtin_amdgcn_mfma_f32_16x16x32_bf16(pu.v, vf1, o1, 0,0,0);
  }
  sum += __shfl_xor(sum,16);
  sum += __shfl_xor(sum,32);
  float rinv = 1.0f/sum;
  // epilogue: lane holds O[q_local=4*lg+r][d=16*td+ll]; rinv for row 4*lg+r at lane 4*lg+r
  #pragma unroll
  for(int r=0;r<4;++r){
    float rl = __shfl(rinv, 4*lg + r);
    int row = q0 + 4*lg + r;
    attnb[((size_t)b*256 + row)*256 + h*32 + ll]      = f2bf(o0[r]*rl);
    attnb[((size_t)b*256 + row)*256 + h*32 + 16 + ll] = f2bf(o1[r]*rl);
  }
}

extern "C" void kernel_launch(void* const* d_in, const int* in_sizes, int n_in,
                              void* d_out, int out_size, void* d_ws, size_t ws_size,
                              hipStream_t stream) {
  const float* x     = (const float*)d_in[0];   // [64][256][256] f32
  const float* w_qkv = (const float*)d_in[1];   // [256][768] f32
  const float* btab  = (const float*)d_in[2];   // [961][8] f32
  const float* w_out = (const float*)d_in[3];   // [256][256] f32
  const float* b_out = (const float*)d_in[4];   // [256] f32
  const int*   ridx  = (const int*)d_in[5];     // [65536] int32
  float* out = (float*)d_out;                   // [64][256][256] f32

  char* ws = (char*)d_ws;
  size_t off = 0;
  u16*   xb     = (u16*)(ws + off); off += (size_t)64*256*256*2;   // 8.39 MB
  u16*   wT     = (u16*)(ws + off); off += (size_t)768*256*2;      // 0.39 MB
  u16*   woT    = (u16*)(ws + off); off += (size_t)256*256*2;      // 0.13 MB
  u16*   biasp2 = (u16*)(ws + off); off += (size_t)524288*2;       // 1.05 MB
  u16*   qkvb   = (u16*)(ws + off); off += (size_t)64*256*768*2;   // 25.17 MB
  u16*   attnb  = (u16*)(ws + off); off += (size_t)64*256*256*2;   // 8.39 MB

  prep_k<<<2048+192+64+2048,256,0,stream>>>(x, xb, w_qkv, wT, w_out, woT, btab, ridx, biasp2);
  gemm_k<false,u16,128><<<dim3(128,6),256,0,stream>>>(xb, wT, nullptr, qkvb, 16384, 768, 256);
  attn_k<<<1024,512,0,stream>>>(qkvb, biasp2, attnb);
  gemm_k<true,float,64><<<dim3(256,2),256,0,stream>>>(attnb, woT, b_out, out, 16384, 256, 256);
}

// Round 16
// 56.559 us; speedup vs baseline: 2.0396x; 1.0936x over previous
//
#include <hip/hip_runtime.h>
#include <hip/hip_bf16.h>

typedef __bf16 bfv8 __attribute__((ext_vector_type(8)));
typedef float f32x4 __attribute__((ext_vector_type(4)));
typedef unsigned short u16;
typedef unsigned int u32;
typedef u16 u16x8 __attribute__((ext_vector_type(8)));

__device__ __forceinline__ float bf2f(u16 u){ union{u32 i; float f;} x; x.i=(u32)u<<16; return x.f; }
__device__ __forceinline__ u16 f2bf(float f){ union{float f; u32 i;} x; x.f=f; u32 i=x.i; return (u16)((i + 0x7FFFu + ((i>>16)&1u))>>16); }

// async global->LDS, 16B per lane: LDS dest = wave-uniform base + lane*16, global src per-lane
__device__ __forceinline__ void gl16(const void* g, void* l){
  __builtin_amdgcn_global_load_lds((const __attribute__((address_space(1))) unsigned int*)g,
                                   (__attribute__((address_space(3))) unsigned int*)l, 16, 0, 0);
}

// ---------- fused prep: cvt x->bf16 | transpose w_qkv | transpose w_out | bias gather ----------
__global__ __launch_bounds__(256) void prep_k(const float* __restrict__ x, u16* __restrict__ xb,
                                              const float* __restrict__ w_qkv, u16* __restrict__ wT,
                                              const float* __restrict__ w_out, u16* __restrict__ woT,
                                              const float* __restrict__ bt, const int* __restrict__ ridx,
                                              u16* __restrict__ biasp2){
  __shared__ u16 tile[32][34];
  const int bid = blockIdx.x, tid = threadIdx.x;
  if (bid < 2048){                       // cvt: 2048*256*8 = 4.19M elems
    int i = (bid*256 + tid)*8;
    float4 a = *(const float4*)&x[i];
    float4 b = *(const float4*)&x[i+4];
    u16 r[8] = { f2bf(a.x),f2bf(a.y),f2bf(a.z),f2bf(a.w), f2bf(b.x),f2bf(b.y),f2bf(b.z),f2bf(b.w) };
    *(int4*)&xb[i] = *(int4*)r;
  } else if (bid < 2048+192){            // transpose w_qkv [256][768] -> wT [768][256]
    int b2 = bid - 2048;
    int c0 = (b2 % 24)*32, r0 = (b2/24)*32;
    int tx = tid & 31, ty = tid >> 5;
    #pragma unroll
    for(int dy=0; dy<32; dy+=8) tile[ty+dy][tx] = f2bf(w_qkv[(size_t)(r0+ty+dy)*768 + (c0+tx)]);
    __syncthreads();
    #pragma unroll
    for(int dy=0; dy<32; dy+=8) wT[(size_t)(c0+ty+dy)*256 + (r0+tx)] = tile[tx][ty+dy];
  } else if (bid < 2048+192+64){         // transpose w_out [256][256] -> woT [256][256]
    int b3 = bid - (2048+192);
    int c0 = (b3 & 7)*32, r0 = (b3 >> 3)*32;
    int tx = tid & 31, ty = tid >> 5;
    #pragma unroll
    for(int dy=0; dy<32; dy+=8) tile[ty+dy][tx] = f2bf(w_out[(size_t)(r0+ty+dy)*256 + (c0+tx)]);
    __syncthreads();
    #pragma unroll
    for(int dy=0; dy<32; dy+=8) woT[(size_t)(c0+ty+dy)*256 + (r0+tx)] = tile[tx][ty+dy];
  } else {                               // bias gather: 524288 bf16, layout [h][rb][lane][ch][e]
    const float L2E = 1.4426950408889634f;
    int idx = (bid - (2048+192+64))*256 + tid;
    int e = idx & 7, ch = (idx>>3)&7, lane = (idx>>6)&63, rb = (idx>>12)&15, h = (idx>>16)&7;
    int ll = lane & 15, lg = lane >> 4;
    int tj = ch*2 + (e>>2), r = e & 3;
    int q = rb*16 + ll, k = 16*tj + 4*lg + r;
    biasp2[idx] = f2bf(bt[ridx[q*256 + k]*8 + h] * L2E);
  }
}

// ---------- m97-style GEMM: C[M][N] = A[M][K]*Bt[N][K]^T (+bias), BK=64, global_load_lds ----------
template<bool BIAS, typename OUT, int TM>
__global__ __launch_bounds__(256) void gemm_k(const u16* __restrict__ A, const u16* __restrict__ Bt,
                         const float* __restrict__ bias, OUT* __restrict__ C, int M, int N, int K){
  constexpr int MI = TM/32;              // M-frags per wave
  __shared__ u16 As[TM*64];              // linear, no padding (global_load_lds requirement)
  __shared__ u16 Bs[128*64];
  const int tid = threadIdx.x, lane = tid & 63, wv = tid >> 6;
  const int lg = lane >> 4, ll = lane & 15;
  const int wr = (wv >> 1)*(TM/2), wc = (wv & 1)*64;
  const size_t m0 = (size_t)blockIdx.x*TM;
  const int n0 = blockIdx.y*128;
  const int lrow = lane >> 3, lcol = (lane & 7)*8;   // 16B/lane: 8 rows x 64 cols per 1KB chunk
  f32x4 acc[MI][4] = {};
  for(int k0=0; k0<K; k0+=64){
    #pragma unroll
    for(int c=0;c<MI;++c){               // A: TM/8 chunks total, MI per wave
      int rowbase = (wv*MI + c)*8;
      gl16(&A[(m0 + rowbase + lrow)*(size_t)K + k0 + lcol], &As[rowbase*64]);
    }
    #pragma unroll
    for(int c=0;c<4;++c){                // B: 16 chunks, 4 per wave
      int rowbase = (wv*4 + c)*8;
      gl16(&Bt[(size_t)(n0 + rowbase + lrow)*K + k0 + lcol], &Bs[rowbase*64]);
    }
    __syncthreads();                     // drains vmcnt(0): staged data visible
    bfv8 af[MI][2], bf[4][2];
    #pragma unroll
    for(int i=0;i<MI;++i)
      #pragma unroll
      for(int kh=0;kh<2;++kh) af[i][kh] = *(const bfv8*)&As[(wr+16*i+ll)*64 + kh*32 + lg*8];
    #pragma unroll
    for(int j=0;j<4;++j)
      #pragma unroll
      for(int kh=0;kh<2;++kh) bf[j][kh] = *(const bfv8*)&Bs[(wc+16*j+ll)*64 + kh*32 + lg*8];
    #pragma unroll
    for(int kh=0;kh<2;++kh)
      #pragma unroll
      for(int i=0;i<MI;++i)
        #pragma unroll
        for(int j=0;j<4;++j)
          acc[i][j] = __builtin_amdgcn_mfma_f32_16x16x32_bf16(af[i][kh], bf[j][kh], acc[i][j], 0,0,0);
    __syncthreads();
  }
  #pragma unroll
  for(int i=0;i<MI;++i)
    #pragma unroll
    for(int j=0;j<4;++j){
      int col = n0 + wc + 16*j + ll;
      float bv = 0.f;
      if (BIAS) bv = bias[col];
      #pragma unroll
      for(int r=0;r<4;++r){
        size_t row = m0 + wr + 16*i + lg*4 + r;
        float v = acc[i][j][r] + bv;
        if constexpr (sizeof(OUT) == 2) C[row*(size_t)N + col] = f2bf(v);
        else                            C[row*(size_t)N + col] = v;
      }
    }
}

// ---------- fused attention per (b,h): 8 waves, stage K/V once, 2 iters of 128 q-rows ----------
// r10-validated version verbatim (best measured): s-array body = max ILP (16 back-to-back
// QK^T MFMAs, batched exp2, batched PV). Eager per-c variant measured +3.4us (r12/r15).
__global__ __launch_bounds__(512) void attn_k(const u16* __restrict__ qkv, const u16* __restrict__ biasp2, u16* __restrict__ attnb){
  __shared__ u16 Ks[256*40];
  __shared__ u16 Vt[32*264];
  const int i = blockIdx.x;
  const int b = i & 63, h = i >> 6;
  const int tid = threadIdx.x, lane = tid & 63, wv = tid >> 6;   // wv in [0,8)
  const int lg = lane >> 4, ll = lane & 15;
  const u16* qb = qkv + (size_t)b*256*768;
  // stage K [256][32] pitch 40 (1024 8-elem chunks, 512 threads x 2)
  #pragma unroll
  for(int p=0;p<2;++p){
    int ch = tid + p*512;
    int j = ch >> 2, d8 = (ch & 3)*8;
    *(int4*)&Ks[j*40 + d8] = *(const int4*)&qb[(size_t)j*768 + 256 + h*32 + d8];
  }
  // stage V^T [32][264] at permuted col jp(k) = 32*(k>>5) + 8*((k>>2)&3) + 4*((k>>4)&1) + (k&3)
  #pragma unroll
  for(int it=0; it<8; ++it){
    int e = tid + it*512;
    int j = e >> 4, dp = (e & 15)*2;
    int jp = ((j>>5)<<5) + 8*((j>>2)&3) + 4*((j>>4)&1) + (j&3);
    u32 v = *(const u32*)&qb[(size_t)j*768 + 512 + h*32 + dp];
    Vt[dp*264 + jp]     = (u16)(v & 0xffffu);
    Vt[(dp+1)*264 + jp] = (u16)(v >> 16);
  }
  __syncthreads();
  const float SCALE2 = 0.17677669529663687f * 1.4426950408889634f;
  const f32x4 zero = {0.f,0.f,0.f,0.f};
  #pragma unroll 1
  for(int iter=0; iter<2; ++iter){
    const int q0 = iter*128 + wv*16;
    // bias: 8 coalesced b128 loads; Q B-fragment
    const u16* bp = biasp2 + ((((size_t)h*16 + (q0>>4))*64 + lane) << 6);
    u16x8 bias[8];
    #pragma unroll
    for(int g=0; g<8; ++g) bias[g] = *(const u16x8*)&bp[g*8];
    bfv8 qf = *(const bfv8*)&qb[(size_t)(q0+ll)*768 + h*32 + lg*8];
    // S^T tiles: s[tj][r] = S[k=16*tj+4*lg+r][q0+ll]
    f32x4 s[16];
    #pragma unroll
    for(int tj=0;tj<16;++tj){
      bfv8 kf = *(const bfv8*)&Ks[(16*tj+ll)*40 + lg*8];
      s[tj] = __builtin_amdgcn_mfma_f32_16x16x32_bf16(kf, qf, zero, 0,0,0);
    }
    // scale + bias (both pre-scaled by log2e), exp2 without shift, lane-local sums
    f32x4 sm = {0.f,0.f,0.f,0.f};
    #pragma unroll
    for(int tj=0;tj<16;++tj){
      #pragma unroll
      for(int r=0;r<4;++r){
        float p = exp2f(fmaf(s[tj][r], SCALE2, bf2f(bias[tj>>1][4*(tj&1)+r])));
        s[tj][r] = p;
        sm[r] += p;
      }
    }
    float sum = sm[0]+sm[1]+sm[2]+sm[3];
    sum += __shfl_xor(sum,16);
    sum += __shfl_xor(sum,32);
    float rinv = 1.0f/sum;
    // pack P to bf16 pairs in-register
    u32 pk[16][2];
    #pragma unroll
    for(int tj=0;tj<16;++tj){
      asm("v_cvt_pk_bf16_f32 %0, %1, %2" : "=v"(pk[tj][0]) : "v"(s[tj][0]), "v"(s[tj][1]));
      asm("v_cvt_pk_bf16_f32 %0, %1, %2" : "=v"(pk[tj][1]) : "v"(s[tj][2]), "v"(s[tj][3]));
    }
    // PV: pf for tile c is the lane's own registers (k-permutation matches Vt staging)
    f32x4 o[2] = {zero, zero};
    #pragma unroll
    for(int c=0;c<8;++c){
      union { u32 u[4]; bfv8 v; } pu;
      pu.u[0] = pk[2*c][0]; pu.u[1] = pk[2*c][1]; pu.u[2] = pk[2*c+1][0]; pu.u[3] = pk[2*c+1][1];
      bfv8 pf = pu.v;
      #pragma unroll
      for(int td=0;td<2;++td){
        bfv8 vf = *(const bfv8*)&Vt[(16*td+ll)*264 + 32*c + lg*8];
        o[td] = __builtin_amdgcn_mfma_f32_16x16x32_bf16(pf, vf, o[td], 0,0,0);
      }
    }
    // epilogue: lane holds O[q_local=4*lg+r][d=16*td+ll]
    #pragma unroll
    for(int td=0;td<2;++td)
      #pragma unroll
      for(int r=0;r<4;++r){
        float rl = __shfl(rinv, 4*lg + r);
        int row = q0 + 4*lg + r;
        attnb[((size_t)b*256 + row)*256 + h*32 + 16*td + ll] = f2bf(o[td][r]*rl);
      }
  }
}

extern "C" void kernel_launch(void* const* d_in, const int* in_sizes, int n_in,
                              void* d_out, int out_size, void* d_ws, size_t ws_size,
                              hipStream_t stream) {
  const float* x     = (const float*)d_in[0];   // [64][256][256] f32
  const float* w_qkv = (const float*)d_in[1];   // [256][768] f32
  const float* btab  = (const float*)d_in[2];   // [961][8] f32
  const float* w_out = (const float*)d_in[3];   // [256][256] f32
  const float* b_out = (const float*)d_in[4];   // [256] f32
  const int*   ridx  = (const int*)d_in[5];     // [65536] int32
  float* out = (float*)d_out;                   // [64][256][256] f32

  char* ws = (char*)d_ws;
  size_t off = 0;
  u16*   xb     = (u16*)(ws + off); off += (size_t)64*256*256*2;   // 8.39 MB
  u16*   wT     = (u16*)(ws + off); off += (size_t)768*256*2;      // 0.39 MB
  u16*   woT    = (u16*)(ws + off); off += (size_t)256*256*2;      // 0.13 MB
  u16*   biasp2 = (u16*)(ws + off); off += (size_t)524288*2;       // 1.05 MB
  u16*   qkvb   = (u16*)(ws + off); off += (size_t)64*256*768*2;   // 25.17 MB
  u16*   attnb  = (u16*)(ws + off); off += (size_t)64*256*256*2;   // 8.39 MB

  prep_k<<<2048+192+64+2048,256,0,stream>>>(x, xb, w_qkv, wT, w_out, woT, btab, ridx, biasp2);
  gemm_k<false,u16,64><<<dim3(256,6),256,0,stream>>>(xb, wT, nullptr, qkvb, 16384, 768, 256);
  attn_k<<<512,512,0,stream>>>(qkvb, biasp2, attnb);
  gemm_k<true,float,32><<<dim3(512,2),256,0,stream>>>(attnb, woT, b_out, out, 16384, 256, 256);
}